// Round 1
// baseline (552.502 us; speedup 1.0000x reference)
//
#include <hip/hip_runtime.h>
#include <hip/hip_bf16.h>

#define B_   32
#define T_   256
#define C_   64
#define H_   128
#define P_   10
#define NS   8
#define NTHR 512

using short8 = __attribute__((ext_vector_type(8))) short;
using f32x4  = __attribute__((ext_vector_type(4))) float;

__device__ __forceinline__ short f2bf(float f) {
  union { float f; unsigned u; } v; v.f = f;
  unsigned r = v.u + 0x7fffu + ((v.u >> 16) & 1u);   // RNE to bf16
  return (short)(r >> 16);
}

__device__ __forceinline__ float fsigmoid(float x) {
  x = fminf(fmaxf(x, -30.f), 30.f);
  return 1.0f / (1.0f + __expf(-x));
}
__device__ __forceinline__ float ftanh(float x) {
  x = fminf(fmaxf(x, -15.f), 15.f);
  float e = __expf(-2.0f * x);
  return (1.0f - e) / (1.0f + e);
}

__global__ __launch_bounds__(NTHR, 2) void gru_fused(
    const float* __restrict__ Z,
    const float* __restrict__ w_ih,
    const float* __restrict__ w_hh,
    const float* __restrict__ b_ih,
    const float* __restrict__ b_hh,
    const float* __restrict__ fc_w,
    const float* __restrict__ fc_b,
    float* __restrict__ out)
{
  __shared__ __align__(16) unsigned short hbuf[2][NS * H_];  // bf16 bits, XOR-swizzled
  __shared__ float hfin[NS][H_];

  const int tid   = threadIdx.x;
  const int wave  = tid >> 6;
  const int lane  = tid & 63;
  const int row16 = lane & 15;     // A row / C col
  const int kgrp  = lane >> 4;     // 0..3
  const int srow  = row16 & 7;     // sequence (rows 8..15 duplicate 0..7)

  const int n0 = blockIdx.x * NS;
  const int bb = n0 >> 6;          // batch index
  const int c0 = n0 & 63;          // channel base
  const int j0 = wave * 16;        // this wave's h-column block
  const int jcol = j0 + row16;     // this lane's h column

  // ---- preload weight B-fragments (bf16, in VGPRs, reused all 256 steps) ----
  short8 wih[3][4], whh[3][4];
  #pragma unroll
  for (int g3 = 0; g3 < 3; ++g3) {
    const int grow = g3 * H_ + jcol;           // weight row = gate output column
    #pragma unroll
    for (int kk = 0; kk < 4; ++kk) {
      const float* p1 = w_ih + grow * H_ + kk * 32 + kgrp * 8;
      const float* p2 = w_hh + grow * H_ + kk * 32 + kgrp * 8;
      short8 a, c;
      #pragma unroll
      for (int e = 0; e < 8; ++e) { a[e] = f2bf(p1[e]); c[e] = f2bf(p2[e]); }
      wih[g3][kk] = a; whh[g3][kk] = c;
    }
  }

  const float bias_r  = b_ih[jcol]          + b_hh[jcol];
  const float bias_z  = b_ih[H_ + jcol]     + b_hh[H_ + jcol];
  const float bias_in = b_ih[2 * H_ + jcol];
  const float bias_hn = b_hh[2 * H_ + jcol];

  f32x4 hreg = {0.f, 0.f, 0.f, 0.f};
  for (int i = tid; i < NS * H_; i += NTHR) hbuf[0][i] = 0;
  __syncthreads();

  // Z[b][t][c][h]; per step the block reads Z[bb][t][c0..c0+7][:] (contiguous 4KB)
  const float* zrow = Z + ((size_t)bb * T_ * C_ + (c0 + srow)) * (size_t)H_ + kgrp * 8;

  auto loadZ = [&](float4 (&zf)[4][2], int t) {
    const float* p = zrow + (size_t)t * (C_ * H_);
    #pragma unroll
    for (int kk = 0; kk < 4; ++kk) {
      zf[kk][0] = *reinterpret_cast<const float4*>(p + kk * 32);
      zf[kk][1] = *reinterpret_cast<const float4*>(p + kk * 32 + 4);
    }
  };

  auto step = [&](int t, float4 (&zcur)[4][2], float4 (&znext)[4][2]) {
    // convert current Z slice to bf16 A-fragments
    short8 za[4];
    #pragma unroll
    for (int kk = 0; kk < 4; ++kk) {
      short8 s;
      s[0] = f2bf(zcur[kk][0].x); s[1] = f2bf(zcur[kk][0].y);
      s[2] = f2bf(zcur[kk][0].z); s[3] = f2bf(zcur[kk][0].w);
      s[4] = f2bf(zcur[kk][1].x); s[5] = f2bf(zcur[kk][1].y);
      s[6] = f2bf(zcur[kk][1].z); s[7] = f2bf(zcur[kk][1].w);
      za[kk] = s;
    }
    // prefetch next step's Z (latency hidden under MFMAs)
    int tn = t + 1; if (tn >= T_) tn = T_ - 1;
    loadZ(znext, tn);

    // h A-fragments from swizzled LDS
    const unsigned short* hb = hbuf[t & 1];
    short8 ha[4];
    #pragma unroll
    for (int kk = 0; kk < 4; ++kk) {
      const int chunk = (kk * 4 + kgrp) ^ srow;
      ha[kk] = *reinterpret_cast<const short8*>(hb + srow * H_ + chunk * 8);
    }

    f32x4 xg[3], hg[3];
    #pragma unroll
    for (int g3 = 0; g3 < 3; ++g3) {
      xg[g3] = (f32x4){0.f, 0.f, 0.f, 0.f};
      hg[g3] = (f32x4){0.f, 0.f, 0.f, 0.f};
    }
    #pragma unroll
    for (int g3 = 0; g3 < 3; ++g3) {
      #pragma unroll
      for (int kk = 0; kk < 4; ++kk) {
        hg[g3] = __builtin_amdgcn_mfma_f32_16x16x32_bf16(ha[kk], whh[g3][kk], hg[g3], 0, 0, 0);
        xg[g3] = __builtin_amdgcn_mfma_f32_16x16x32_bf16(za[kk], wih[g3][kk], xg[g3], 0, 0, 0);
      }
    }

    // gates + state update (all three gates for column jcol live in this lane)
    unsigned short* hw = hbuf[(t + 1) & 1];
    f32x4 hnew;
    #pragma unroll
    for (int i = 0; i < 4; ++i) {
      float r  = fsigmoid(xg[0][i] + hg[0][i] + bias_r);
      float zt = fsigmoid(xg[1][i] + hg[1][i] + bias_z);
      float nn = ftanh(xg[2][i] + bias_in + r * (hg[2][i] + bias_hn));
      hnew[i] = nn + zt * (hreg[i] - nn);
    }
    hreg = hnew;
    if (kgrp < 2) {
      #pragma unroll
      for (int i = 0; i < 4; ++i) {
        const int r = kgrp * 4 + i;                       // sequence row 0..7
        const int idx = r * H_ + (((jcol >> 3) ^ r) * 8) + (jcol & 7);
        hw[idx] = (unsigned short)f2bf(hnew[i]);
      }
    }
    __syncthreads();
  };

  float4 zA[4][2], zB[4][2];
  loadZ(zA, 0);
  for (int t = 0; t < T_; t += 2) {
    step(t,     zA, zB);
    step(t + 1, zB, zA);
  }

  // ---- FC head: pred[n][p] = h_last[n] . fc_w[p] + fc_b[p] ----
  if (kgrp < 2) {
    #pragma unroll
    for (int i = 0; i < 4; ++i) hfin[kgrp * 4 + i][jcol] = hreg[i];
  }
  __syncthreads();

  if (tid < NS * P_) {
    const int s = tid / P_, p = tid % P_;
    float acc = fc_b[p];
    const float* fw = fc_w + p * H_;
    #pragma unroll 8
    for (int j = 0; j < H_; ++j) acc += hfin[s][j] * fw[j];
    // out[b][p][c]
    out[((size_t)bb * P_ + p) * C_ + (c0 + s)] = acc;
  }
}

extern "C" void kernel_launch(void* const* d_in, const int* in_sizes, int n_in,
                              void* d_out, int out_size, void* d_ws, size_t ws_size,
                              hipStream_t stream) {
  const float* Z    = (const float*)d_in[0];
  const float* w_ih = (const float*)d_in[1];
  const float* w_hh = (const float*)d_in[2];
  const float* b_ih = (const float*)d_in[3];
  const float* b_hh = (const float*)d_in[4];
  const float* fc_w = (const float*)d_in[5];
  const float* fc_b = (const float*)d_in[6];
  float* out = (float*)d_out;

  dim3 grid((B_ * C_) / NS);   // 256 blocks, one per CU
  gru_fused<<<grid, NTHR, 0, stream>>>(Z, w_ih, w_hh, b_ih, b_hh, fc_w, fc_b, out);
}

// Round 2
// 316.615 us; speedup vs baseline: 1.7450x; 1.7450x over previous
//
#include <hip/hip_runtime.h>
#include <hip/hip_bf16.h>

#define B_   32
#define T_   256
#define C_   64
#define H_   128
#define P_   10
#define N_   (B_ * C_)
#define NS   8
#define NTHR 512

using short8 = __attribute__((ext_vector_type(8))) short;
using f32x4  = __attribute__((ext_vector_type(4))) float;

__device__ __forceinline__ short f2bf(float f) {
  union { float f; unsigned u; } v; v.f = f;
  unsigned r = v.u + 0x7fffu + ((v.u >> 16) & 1u);   // RNE to bf16
  return (short)(r >> 16);
}

__device__ __forceinline__ float frcp(float x) { return __builtin_amdgcn_rcpf(x); }

// ---------------- Pass 1: Z (B,T,C,H) fp32 -> Zt (T, B*C, H) bf16 ----------------
__global__ __launch_bounds__(256) void zconv(const float* __restrict__ Z,
                                             unsigned short* __restrict__ Zt) {
  const int blk = blockIdx.x;          // B_*T_ blocks
  const int b = blk >> 8;              // / T_
  const int t = blk & (T_ - 1);
  const float* src = Z + ((size_t)(b * T_ + t)) * (C_ * H_);
  unsigned short* dst = Zt + ((size_t)(t * B_ + b)) * (C_ * H_);
  #pragma unroll
  for (int i = 0; i < 8; ++i) {
    const int idx = threadIdx.x + i * 256;             // float4 index, 2048 total
    float4 v = reinterpret_cast<const float4*>(src)[idx];
    short4 o;
    o.x = f2bf(v.x); o.y = f2bf(v.y); o.z = f2bf(v.z); o.w = f2bf(v.w);
    reinterpret_cast<short4*>(dst)[idx] = o;
  }
}

// ---------------- Pass 2: persistent GRU scan over Zt ----------------
__global__ __launch_bounds__(NTHR, 2) void gru2(
    const unsigned short* __restrict__ Zt,
    const float* __restrict__ w_ih,
    const float* __restrict__ w_hh,
    const float* __restrict__ b_ih,
    const float* __restrict__ b_hh,
    const float* __restrict__ fc_w,
    const float* __restrict__ fc_b,
    float* __restrict__ out)
{
  __shared__ __align__(16) unsigned short hbuf[2][NS * H_];  // bf16 bits, XOR-swizzled
  __shared__ float hfin[NS][H_];

  const int tid   = threadIdx.x;
  const int wave  = tid >> 6;
  const int lane  = tid & 63;
  const int row16 = lane & 15;
  const int kgrp  = lane >> 4;
  const int srow  = row16 & 7;

  const int n0 = blockIdx.x * NS;
  const int bb = n0 >> 6;
  const int c0 = n0 & 63;
  const int jcol = wave * 16 + row16;

  // ---- weight B-fragments in VGPRs (reused all 256 steps) ----
  short8 wih[3][4], whh[3][4];
  #pragma unroll
  for (int g3 = 0; g3 < 3; ++g3) {
    const int grow = g3 * H_ + jcol;
    #pragma unroll
    for (int kk = 0; kk < 4; ++kk) {
      const float* p1 = w_ih + grow * H_ + kk * 32 + kgrp * 8;
      const float* p2 = w_hh + grow * H_ + kk * 32 + kgrp * 8;
      short8 a, c;
      #pragma unroll
      for (int e = 0; e < 8; ++e) { a[e] = f2bf(p1[e]); c[e] = f2bf(p2[e]); }
      wih[g3][kk] = a; whh[g3][kk] = c;
    }
  }

  const float bias_r  = b_ih[jcol]          + b_hh[jcol];
  const float bias_z  = b_ih[H_ + jcol]     + b_hh[H_ + jcol];
  const float bias_in = b_ih[2 * H_ + jcol];
  const float bias_hn = b_hh[2 * H_ + jcol];

  f32x4 hreg = {0.f, 0.f, 0.f, 0.f};
  for (int i = tid; i < NS * H_; i += NTHR) hbuf[0][i] = 0;
  __syncthreads();

  // per-lane Z base: A-frag row = srow, k = kk*32 + kgrp*8 + e
  const unsigned short* zb = Zt + (size_t)(n0 + srow) * H_ + kgrp * 8;

  auto loadZ = [&](short8 (&dst)[4], int t) {
    const unsigned short* p = zb + (size_t)t * (N_ * H_);
    #pragma unroll
    for (int kk = 0; kk < 4; ++kk)
      dst[kk] = *reinterpret_cast<const short8*>(p + kk * 32);
  };

  short8 zs[4][4];

  auto step = [&](int t, short8 (&za)[4], short8 (&znx)[4], int tl) {
    if (tl > T_ - 1) tl = T_ - 1;
    loadZ(znx, tl);                       // prefetch 2 steps ahead (survives barrier)

    // h A-fragments from swizzled LDS
    const unsigned short* hb = hbuf[t & 1];
    short8 ha[4];
    #pragma unroll
    for (int kk = 0; kk < 4; ++kk) {
      const int chunk = (kk * 4 + kgrp) ^ srow;
      ha[kk] = *reinterpret_cast<const short8*>(hb + srow * H_ + chunk * 8);
    }

    f32x4 xg[3], hg[3];
    xg[0] = (f32x4){0.f, 0.f, 0.f, 0.f};
    xg[1] = (f32x4){0.f, 0.f, 0.f, 0.f};
    xg[2] = (f32x4){bias_in, bias_in, bias_in, bias_in};
    hg[0] = (f32x4){bias_r, bias_r, bias_r, bias_r};
    hg[1] = (f32x4){bias_z, bias_z, bias_z, bias_z};
    hg[2] = (f32x4){bias_hn, bias_hn, bias_hn, bias_hn};

    // x-projection first (za already in regs), then h-projection (hides ds_read)
    #pragma unroll
    for (int g3 = 0; g3 < 3; ++g3)
      #pragma unroll
      for (int kk = 0; kk < 4; ++kk)
        xg[g3] = __builtin_amdgcn_mfma_f32_16x16x32_bf16(za[kk], wih[g3][kk], xg[g3], 0, 0, 0);
    #pragma unroll
    for (int g3 = 0; g3 < 3; ++g3)
      #pragma unroll
      for (int kk = 0; kk < 4; ++kk)
        hg[g3] = __builtin_amdgcn_mfma_f32_16x16x32_bf16(ha[kk], whh[g3][kk], hg[g3], 0, 0, 0);

    unsigned short* hw = hbuf[(t + 1) & 1];
    f32x4 hnew;
    #pragma unroll
    for (int i = 0; i < 4; ++i) {
      float r  = frcp(1.0f + __expf(-(xg[0][i] + hg[0][i])));
      float zt = frcp(1.0f + __expf(-(xg[1][i] + hg[1][i])));
      float a  = xg[2][i] + r * hg[2][i];
      float nn = 2.0f * frcp(1.0f + __expf(-2.0f * a)) - 1.0f;   // tanh(a)
      hnew[i]  = nn + zt * (hreg[i] - nn);
    }
    hreg = hnew;
    if (kgrp < 2) {
      #pragma unroll
      for (int i = 0; i < 4; ++i) {
        const int r = kgrp * 4 + i;
        const int idx = r * H_ + (((jcol >> 3) ^ r) * 8) + (jcol & 7);
        hw[idx] = (unsigned short)f2bf(hnew[i]);
      }
    }
    // raw barrier: drain LDS writes only, keep global prefetch in flight
    asm volatile("s_waitcnt lgkmcnt(0)" ::: "memory");
    __builtin_amdgcn_s_barrier();
    __builtin_amdgcn_sched_barrier(0);
  };

  loadZ(zs[0], 0);
  loadZ(zs[1], 1);
  for (int t = 0; t < T_; t += 4) {
    step(t + 0, zs[0], zs[2], t + 2);
    step(t + 1, zs[1], zs[3], t + 3);
    step(t + 2, zs[2], zs[0], t + 4);
    step(t + 3, zs[3], zs[1], t + 5);
  }

  // ---- FC head ----
  if (kgrp < 2) {
    #pragma unroll
    for (int i = 0; i < 4; ++i) hfin[kgrp * 4 + i][jcol] = hreg[i];
  }
  __syncthreads();

  if (tid < NS * P_) {
    const int s = tid / P_, p = tid % P_;
    float acc = fc_b[p];
    const float* fw = fc_w + p * H_;
    #pragma unroll 8
    for (int j = 0; j < H_; ++j) acc += hfin[s][j] * fw[j];
    out[((size_t)bb * P_ + p) * C_ + (c0 + s)] = acc;
  }
}

// ---------------- Fallback (round-1 fused kernel, used only if ws too small) ----------------
__device__ __forceinline__ float fsigmoid(float x) {
  x = fminf(fmaxf(x, -30.f), 30.f);
  return 1.0f / (1.0f + __expf(-x));
}
__device__ __forceinline__ float ftanh(float x) {
  x = fminf(fmaxf(x, -15.f), 15.f);
  float e = __expf(-2.0f * x);
  return (1.0f - e) / (1.0f + e);
}

__global__ __launch_bounds__(NTHR, 2) void gru_fused(
    const float* __restrict__ Z,
    const float* __restrict__ w_ih,
    const float* __restrict__ w_hh,
    const float* __restrict__ b_ih,
    const float* __restrict__ b_hh,
    const float* __restrict__ fc_w,
    const float* __restrict__ fc_b,
    float* __restrict__ out)
{
  __shared__ __align__(16) unsigned short hbuf[2][NS * H_];
  __shared__ float hfin[NS][H_];

  const int tid   = threadIdx.x;
  const int wave  = tid >> 6;
  const int lane  = tid & 63;
  const int row16 = lane & 15;
  const int kgrp  = lane >> 4;
  const int srow  = row16 & 7;

  const int n0 = blockIdx.x * NS;
  const int bb = n0 >> 6;
  const int c0 = n0 & 63;
  const int jcol = wave * 16 + row16;

  short8 wih[3][4], whh[3][4];
  #pragma unroll
  for (int g3 = 0; g3 < 3; ++g3) {
    const int grow = g3 * H_ + jcol;
    #pragma unroll
    for (int kk = 0; kk < 4; ++kk) {
      const float* p1 = w_ih + grow * H_ + kk * 32 + kgrp * 8;
      const float* p2 = w_hh + grow * H_ + kk * 32 + kgrp * 8;
      short8 a, c;
      #pragma unroll
      for (int e = 0; e < 8; ++e) { a[e] = f2bf(p1[e]); c[e] = f2bf(p2[e]); }
      wih[g3][kk] = a; whh[g3][kk] = c;
    }
  }

  const float bias_r  = b_ih[jcol]          + b_hh[jcol];
  const float bias_z  = b_ih[H_ + jcol]     + b_hh[H_ + jcol];
  const float bias_in = b_ih[2 * H_ + jcol];
  const float bias_hn = b_hh[2 * H_ + jcol];

  f32x4 hreg = {0.f, 0.f, 0.f, 0.f};
  for (int i = tid; i < NS * H_; i += NTHR) hbuf[0][i] = 0;
  __syncthreads();

  const float* zrow = Z + ((size_t)bb * T_ * C_ + (c0 + srow)) * (size_t)H_ + kgrp * 8;

  auto loadZ = [&](float4 (&zf)[4][2], int t) {
    const float* p = zrow + (size_t)t * (C_ * H_);
    #pragma unroll
    for (int kk = 0; kk < 4; ++kk) {
      zf[kk][0] = *reinterpret_cast<const float4*>(p + kk * 32);
      zf[kk][1] = *reinterpret_cast<const float4*>(p + kk * 32 + 4);
    }
  };

  auto step = [&](int t, float4 (&zcur)[4][2], float4 (&znext)[4][2]) {
    short8 za[4];
    #pragma unroll
    for (int kk = 0; kk < 4; ++kk) {
      short8 s;
      s[0] = f2bf(zcur[kk][0].x); s[1] = f2bf(zcur[kk][0].y);
      s[2] = f2bf(zcur[kk][0].z); s[3] = f2bf(zcur[kk][0].w);
      s[4] = f2bf(zcur[kk][1].x); s[5] = f2bf(zcur[kk][1].y);
      s[6] = f2bf(zcur[kk][1].z); s[7] = f2bf(zcur[kk][1].w);
      za[kk] = s;
    }
    int tn = t + 1; if (tn >= T_) tn = T_ - 1;
    loadZ(znext, tn);

    const unsigned short* hb = hbuf[t & 1];
    short8 ha[4];
    #pragma unroll
    for (int kk = 0; kk < 4; ++kk) {
      const int chunk = (kk * 4 + kgrp) ^ srow;
      ha[kk] = *reinterpret_cast<const short8*>(hb + srow * H_ + chunk * 8);
    }

    f32x4 xg[3], hg[3];
    #pragma unroll
    for (int g3 = 0; g3 < 3; ++g3) {
      xg[g3] = (f32x4){0.f, 0.f, 0.f, 0.f};
      hg[g3] = (f32x4){0.f, 0.f, 0.f, 0.f};
    }
    #pragma unroll
    for (int g3 = 0; g3 < 3; ++g3) {
      #pragma unroll
      for (int kk = 0; kk < 4; ++kk) {
        hg[g3] = __builtin_amdgcn_mfma_f32_16x16x32_bf16(ha[kk], whh[g3][kk], hg[g3], 0, 0, 0);
        xg[g3] = __builtin_amdgcn_mfma_f32_16x16x32_bf16(za[kk], wih[g3][kk], xg[g3], 0, 0, 0);
      }
    }

    unsigned short* hw = hbuf[(t + 1) & 1];
    f32x4 hnew;
    #pragma unroll
    for (int i = 0; i < 4; ++i) {
      float r  = fsigmoid(xg[0][i] + hg[0][i] + bias_r);
      float zt = fsigmoid(xg[1][i] + hg[1][i] + bias_z);
      float nn = ftanh(xg[2][i] + bias_in + r * (hg[2][i] + bias_hn));
      hnew[i] = nn + zt * (hreg[i] - nn);
    }
    hreg = hnew;
    if (kgrp < 2) {
      #pragma unroll
      for (int i = 0; i < 4; ++i) {
        const int r = kgrp * 4 + i;
        const int idx = r * H_ + (((jcol >> 3) ^ r) * 8) + (jcol & 7);
        hw[idx] = (unsigned short)f2bf(hnew[i]);
      }
    }
    __syncthreads();
  };

  float4 zA[4][2], zB[4][2];
  loadZ(zA, 0);
  for (int t = 0; t < T_; t += 2) {
    step(t,     zA, zB);
    step(t + 1, zB, zA);
  }

  if (kgrp < 2) {
    #pragma unroll
    for (int i = 0; i < 4; ++i) hfin[kgrp * 4 + i][jcol] = hreg[i];
  }
  __syncthreads();

  if (tid < NS * P_) {
    const int s = tid / P_, p = tid % P_;
    float acc = fc_b[p];
    const float* fw = fc_w + p * H_;
    #pragma unroll 8
    for (int j = 0; j < H_; ++j) acc += hfin[s][j] * fw[j];
    out[((size_t)bb * P_ + p) * C_ + (c0 + s)] = acc;
  }
}

extern "C" void kernel_launch(void* const* d_in, const int* in_sizes, int n_in,
                              void* d_out, int out_size, void* d_ws, size_t ws_size,
                              hipStream_t stream) {
  const float* Z    = (const float*)d_in[0];
  const float* w_ih = (const float*)d_in[1];
  const float* w_hh = (const float*)d_in[2];
  const float* b_ih = (const float*)d_in[3];
  const float* b_hh = (const float*)d_in[4];
  const float* fc_w = (const float*)d_in[5];
  const float* fc_b = (const float*)d_in[6];
  float* out = (float*)d_out;

  const size_t zt_bytes = (size_t)T_ * N_ * H_ * 2;   // 128 MiB
  if (ws_size >= zt_bytes) {
    unsigned short* Zt = (unsigned short*)d_ws;
    zconv<<<dim3(B_ * T_), 256, 0, stream>>>(Z, Zt);
    gru2<<<dim3(N_ / NS), NTHR, 0, stream>>>(Zt, w_ih, w_hh, b_ih, b_hh, fc_w, fc_b, out);
  } else {
    gru_fused<<<dim3(N_ / NS), NTHR, 0, stream>>>(Z, w_ih, w_hh, b_ih, b_hh, fc_w, fc_b, out);
  }
}

// Round 3
// 278.828 us; speedup vs baseline: 1.9815x; 1.1355x over previous
//
#include <hip/hip_runtime.h>
#include <hip/hip_bf16.h>

#define B_   32
#define T_   256
#define C_   64
#define H_   128
#define P_   10
#define N_   (B_ * C_)
#define NS   8
#define NTHR 512
#define T2   (T_ / 2)

using short8 = __attribute__((ext_vector_type(8))) short;
using f32x4  = __attribute__((ext_vector_type(4))) float;

__device__ __forceinline__ short f2bf(float f) {
  union { float f; unsigned u; } v; v.f = f;
  unsigned r = v.u + 0x7fffu + ((v.u >> 16) & 1u);   // RNE to bf16
  return (short)(r >> 16);
}
__device__ __forceinline__ float frcp(float x) { return __builtin_amdgcn_rcpf(x); }

// ---------------- Pass 1: Z (B,T,C,H) fp32 -> Zt (T, B*C, H) bf16 ----------------
__global__ __launch_bounds__(256) void zconv(const float* __restrict__ Z,
                                             unsigned short* __restrict__ Zt) {
  const int blk = blockIdx.x;
  const int b = blk >> 8;
  const int t = blk & (T_ - 1);
  const float* src = Z + ((size_t)(b * T_ + t)) * (C_ * H_);
  unsigned short* dst = Zt + ((size_t)(t * B_ + b)) * (C_ * H_);
  #pragma unroll
  for (int i = 0; i < 8; ++i) {
    const int idx = threadIdx.x + i * 256;
    float4 v = reinterpret_cast<const float4*>(src)[idx];
    short4 o;
    o.x = f2bf(v.x); o.y = f2bf(v.y); o.z = f2bf(v.z); o.w = f2bf(v.w);
    reinterpret_cast<short4*>(dst)[idx] = o;
  }
}

// ---------------- Pass 2: persistent GRU, 2 time-steps per xg MFMA pass ----------------
__global__ __launch_bounds__(NTHR, 2) void gru3(
    const unsigned short* __restrict__ Zt,
    const float* __restrict__ w_ih,
    const float* __restrict__ w_hh,
    const float* __restrict__ b_ih,
    const float* __restrict__ b_hh,
    const float* __restrict__ fc_w,
    const float* __restrict__ fc_b,
    float* __restrict__ out)
{
  __shared__ __align__(16) unsigned short hbuf[2][NS * H_];
  __shared__ float hfin[NS][H_];

  const int tid   = threadIdx.x;
  const int wave  = tid >> 6;
  const int lane  = tid & 63;
  const int row16 = lane & 15;
  const int kgrp  = lane >> 4;
  const int srow  = row16 & 7;
  const int thalf = row16 >> 3;          // A-rows 0-7: step t, rows 8-15: step t+1

  const int n0 = blockIdx.x * NS;
  const int bb = n0 >> 6;
  const int c0 = n0 & 63;
  const int jcol = wave * 16 + row16;

  // ---- weight B-fragments in VGPRs ----
  short8 wih[3][4], whh[3][4];
  #pragma unroll
  for (int g3 = 0; g3 < 3; ++g3) {
    const int grow = g3 * H_ + jcol;
    #pragma unroll
    for (int kk = 0; kk < 4; ++kk) {
      const float* p1 = w_ih + grow * H_ + kk * 32 + kgrp * 8;
      const float* p2 = w_hh + grow * H_ + kk * 32 + kgrp * 8;
      short8 a, c;
      #pragma unroll
      for (int e = 0; e < 8; ++e) { a[e] = f2bf(p1[e]); c[e] = f2bf(p2[e]); }
      wih[g3][kk] = a; whh[g3][kk] = c;
    }
  }

  const float bias_r  = b_ih[jcol]          + b_hh[jcol];
  const float bias_z  = b_ih[H_ + jcol]     + b_hh[H_ + jcol];
  const float bias_in = b_ih[2 * H_ + jcol];
  const float bias_hn = b_hh[2 * H_ + jcol];

  for (int i = tid; i < NS * H_; i += NTHR) hbuf[0][i] = 0;
  __syncthreads();

  // ---- hoisted LDS addresses (swizzled) ----
  const unsigned short* haP[2][4];   // read: A-frag for h, per parity / kk
  unsigned short*       hwP[2][4];   // write: 4 rows per lane-half, per parity
  #pragma unroll
  for (int par = 0; par < 2; ++par) {
    #pragma unroll
    for (int kk = 0; kk < 4; ++kk) {
      const int chunk = (kk * 4 + kgrp) ^ srow;
      haP[par][kk] = &hbuf[par][srow * H_ + chunk * 8];
    }
    #pragma unroll
    for (int i = 0; i < 4; ++i) {
      const int r = (kgrp & 1) * 4 + i;
      hwP[par][i] = &hbuf[par][r * H_ + (((jcol >> 3) ^ r) * 8) + (jcol & 7)];
    }
  }

  // per-lane Z base: row16<8 -> step 2p, row16>=8 -> step 2p+1
  const unsigned short* zb = Zt + (size_t)thalf * (N_ * H_)
                               + (size_t)(n0 + srow) * H_ + kgrp * 8;
  auto loadPair = [&](short8 (&dst)[4], int p) {
    if (p > T2 - 1) p = T2 - 1;
    const unsigned short* q = zb + (size_t)(2 * p) * (N_ * H_);
    #pragma unroll
    for (int kk = 0; kk < 4; ++kk)
      dst[kk] = *reinterpret_cast<const short8*>(q + kk * 32);
  };

  auto xgFill01 = [&](f32x4 (&xg)[3], short8 (&z)[4]) {
    xg[0] = (f32x4){0.f, 0.f, 0.f, 0.f};
    xg[1] = (f32x4){0.f, 0.f, 0.f, 0.f};
    #pragma unroll
    for (int g3 = 0; g3 < 2; ++g3)
      #pragma unroll
      for (int kk = 0; kk < 4; ++kk)
        xg[g3] = __builtin_amdgcn_mfma_f32_16x16x32_bf16(z[kk], wih[g3][kk], xg[g3], 0, 0, 0);
  };
  auto xgFill2 = [&](f32x4 (&xg)[3], short8 (&z)[4]) {
    xg[2] = (f32x4){bias_in, bias_in, bias_in, bias_in};
    #pragma unroll
    for (int kk = 0; kk < 4; ++kk)
      xg[2] = __builtin_amdgcn_mfma_f32_16x16x32_bf16(z[kk], wih[2][kk], xg[2], 0, 0, 0);
  };
  auto hgMFMA = [&](const unsigned short* const (&hp)[4], f32x4 (&hg)[3]) {
    short8 ha[4];
    #pragma unroll
    for (int kk = 0; kk < 4; ++kk)
      ha[kk] = *reinterpret_cast<const short8*>(hp[kk]);
    hg[0] = (f32x4){bias_r,  bias_r,  bias_r,  bias_r};
    hg[1] = (f32x4){bias_z,  bias_z,  bias_z,  bias_z};
    hg[2] = (f32x4){bias_hn, bias_hn, bias_hn, bias_hn};
    #pragma unroll
    for (int g3 = 0; g3 < 3; ++g3)
      #pragma unroll
      for (int kk = 0; kk < 4; ++kk)
        hg[g3] = __builtin_amdgcn_mfma_f32_16x16x32_bf16(ha[kk], whh[g3][kk], hg[g3], 0, 0, 0);
  };
  auto gates = [&](f32x4 (&xg)[3], f32x4 (&hg)[3], f32x4 hprev) -> f32x4 {
    f32x4 hn;
    #pragma unroll
    for (int i = 0; i < 4; ++i) {
      float r  = frcp(1.0f + __expf(-(xg[0][i] + hg[0][i])));
      float zt = frcp(1.0f + __expf(-(xg[1][i] + hg[1][i])));
      float a  = xg[2][i] + r * hg[2][i];
      float nn = 2.0f * frcp(1.0f + __expf(-2.0f * a)) - 1.0f;
      hn[i] = nn + zt * (hprev[i] - nn);
    }
    return hn;
  };

  #define BAR() do { asm volatile("s_waitcnt lgkmcnt(0)" ::: "memory"); \
                     __builtin_amdgcn_s_barrier(); \
                     __builtin_amdgcn_sched_barrier(0); } while (0)

  f32x4 hlo = {0.f, 0.f, 0.f, 0.f};     // h state fp32, valid on lanes<32 (seq = kgrp*4+i)
  short8 zf0[4], zf1[4];
  f32x4 xgA[3], xgB[3];

  loadPair(zf0, 0);
  loadPair(zf1, 1);
  // prologue: xgA <- pair 0
  xgA[0] = (f32x4){0.f, 0.f, 0.f, 0.f};
  xgA[1] = (f32x4){0.f, 0.f, 0.f, 0.f};
  xgA[2] = (f32x4){bias_in, bias_in, bias_in, bias_in};
  #pragma unroll
  for (int g3 = 0; g3 < 3; ++g3)
    #pragma unroll
    for (int kk = 0; kk < 4; ++kk)
      xgA[g3] = __builtin_amdgcn_mfma_f32_16x16x32_bf16(zf0[kk], wih[g3][kk], xgA[g3], 0, 0, 0);

  for (int p = 0; p < T2; p += 2) {
    // ======== pair p (steps 2p, 2p+1): uses xgA, fills xgB from zf1, reloads zf0 ========
    loadPair(zf0, p + 2);
    {
      xgFill01(xgB, zf1);
      f32x4 hg[3];
      hgMFMA(haP[0], hg);
      f32x4 hA = gates(xgA, hg, hlo);              // valid lanes<32
      if (kgrp < 2) {
        #pragma unroll
        for (int i = 0; i < 4; ++i) *hwP[1][i] = (unsigned short)f2bf(hA[i]);
      }
      f32x4 hup;
      #pragma unroll
      for (int i = 0; i < 4; ++i) hup[i] = __shfl_xor(hA[i], 32, 64);
      BAR();
      xgFill2(xgB, zf1);
      f32x4 hg2[3];
      hgMFMA(haP[1], hg2);
      f32x4 hB = gates(xgA, hg2, hup);             // valid lanes>=32 (xgA rows 8-15 = t+1)
      if (kgrp >= 2) {
        #pragma unroll
        for (int i = 0; i < 4; ++i) *hwP[0][i] = (unsigned short)f2bf(hB[i]);
      }
      #pragma unroll
      for (int i = 0; i < 4; ++i) hlo[i] = __shfl_xor(hB[i], 32, 64);
      BAR();
    }
    // ======== pair p+1 (steps 2p+2, 2p+3): uses xgB, fills xgA from zf0, reloads zf1 ========
    loadPair(zf1, p + 3);
    {
      xgFill01(xgA, zf0);
      f32x4 hg[3];
      hgMFMA(haP[0], hg);
      f32x4 hA = gates(xgB, hg, hlo);
      if (kgrp < 2) {
        #pragma unroll
        for (int i = 0; i < 4; ++i) *hwP[1][i] = (unsigned short)f2bf(hA[i]);
      }
      f32x4 hup;
      #pragma unroll
      for (int i = 0; i < 4; ++i) hup[i] = __shfl_xor(hA[i], 32, 64);
      BAR();
      xgFill2(xgA, zf0);
      f32x4 hg2[3];
      hgMFMA(haP[1], hg2);
      f32x4 hB = gates(xgB, hg2, hup);
      if (kgrp >= 2) {
        #pragma unroll
        for (int i = 0; i < 4; ++i) *hwP[0][i] = (unsigned short)f2bf(hB[i]);
      }
      #pragma unroll
      for (int i = 0; i < 4; ++i) hlo[i] = __shfl_xor(hB[i], 32, 64);
      BAR();
    }
  }
  #undef BAR

  // ---- FC head ----
  if (kgrp < 2) {
    #pragma unroll
    for (int i = 0; i < 4; ++i) hfin[kgrp * 4 + i][jcol] = hlo[i];
  }
  __syncthreads();

  if (tid < NS * P_) {
    const int s = tid / P_, p = tid % P_;
    float acc = fc_b[p];
    const float* fw = fc_w + p * H_;
    #pragma unroll 8
    for (int j = 0; j < H_; ++j) acc += hfin[s][j] * fw[j];
    out[((size_t)bb * P_ + p) * C_ + (c0 + s)] = acc;
  }
}

// ---------------- Fallback (round-1 fused kernel, only if ws too small) ----------------
__device__ __forceinline__ float fsigmoid(float x) {
  x = fminf(fmaxf(x, -30.f), 30.f);
  return 1.0f / (1.0f + __expf(-x));
}
__device__ __forceinline__ float ftanh(float x) {
  x = fminf(fmaxf(x, -15.f), 15.f);
  float e = __expf(-2.0f * x);
  return (1.0f - e) / (1.0f + e);
}

__global__ __launch_bounds__(NTHR, 2) void gru_fused(
    const float* __restrict__ Z,
    const float* __restrict__ w_ih,
    const float* __restrict__ w_hh,
    const float* __restrict__ b_ih,
    const float* __restrict__ b_hh,
    const float* __restrict__ fc_w,
    const float* __restrict__ fc_b,
    float* __restrict__ out)
{
  __shared__ __align__(16) unsigned short hbuf[2][NS * H_];
  __shared__ float hfin[NS][H_];

  const int tid   = threadIdx.x;
  const int wave  = tid >> 6;
  const int lane  = tid & 63;
  const int row16 = lane & 15;
  const int kgrp  = lane >> 4;
  const int srow  = row16 & 7;

  const int n0 = blockIdx.x * NS;
  const int bb = n0 >> 6;
  const int c0 = n0 & 63;
  const int jcol = wave * 16 + row16;

  short8 wih[3][4], whh[3][4];
  #pragma unroll
  for (int g3 = 0; g3 < 3; ++g3) {
    const int grow = g3 * H_ + jcol;
    #pragma unroll
    for (int kk = 0; kk < 4; ++kk) {
      const float* p1 = w_ih + grow * H_ + kk * 32 + kgrp * 8;
      const float* p2 = w_hh + grow * H_ + kk * 32 + kgrp * 8;
      short8 a, c;
      #pragma unroll
      for (int e = 0; e < 8; ++e) { a[e] = f2bf(p1[e]); c[e] = f2bf(p2[e]); }
      wih[g3][kk] = a; whh[g3][kk] = c;
    }
  }

  const float bias_r  = b_ih[jcol]          + b_hh[jcol];
  const float bias_z  = b_ih[H_ + jcol]     + b_hh[H_ + jcol];
  const float bias_in = b_ih[2 * H_ + jcol];
  const float bias_hn = b_hh[2 * H_ + jcol];

  f32x4 hreg = {0.f, 0.f, 0.f, 0.f};
  for (int i = tid; i < NS * H_; i += NTHR) hbuf[0][i] = 0;
  __syncthreads();

  const float* zrow = Z + ((size_t)bb * T_ * C_ + (c0 + srow)) * (size_t)H_ + kgrp * 8;

  auto loadZ = [&](float4 (&zf)[4][2], int t) {
    const float* p = zrow + (size_t)t * (C_ * H_);
    #pragma unroll
    for (int kk = 0; kk < 4; ++kk) {
      zf[kk][0] = *reinterpret_cast<const float4*>(p + kk * 32);
      zf[kk][1] = *reinterpret_cast<const float4*>(p + kk * 32 + 4);
    }
  };

  auto step = [&](int t, float4 (&zcur)[4][2], float4 (&znext)[4][2]) {
    short8 za[4];
    #pragma unroll
    for (int kk = 0; kk < 4; ++kk) {
      short8 s;
      s[0] = f2bf(zcur[kk][0].x); s[1] = f2bf(zcur[kk][0].y);
      s[2] = f2bf(zcur[kk][0].z); s[3] = f2bf(zcur[kk][0].w);
      s[4] = f2bf(zcur[kk][1].x); s[5] = f2bf(zcur[kk][1].y);
      s[6] = f2bf(zcur[kk][1].z); s[7] = f2bf(zcur[kk][1].w);
      za[kk] = s;
    }
    int tn = t + 1; if (tn >= T_) tn = T_ - 1;
    loadZ(znext, tn);

    const unsigned short* hb = hbuf[t & 1];
    short8 ha[4];
    #pragma unroll
    for (int kk = 0; kk < 4; ++kk) {
      const int chunk = (kk * 4 + kgrp) ^ srow;
      ha[kk] = *reinterpret_cast<const short8*>(hb + srow * H_ + chunk * 8);
    }

    f32x4 xg[3], hg[3];
    #pragma unroll
    for (int g3 = 0; g3 < 3; ++g3) {
      xg[g3] = (f32x4){0.f, 0.f, 0.f, 0.f};
      hg[g3] = (f32x4){0.f, 0.f, 0.f, 0.f};
    }
    #pragma unroll
    for (int g3 = 0; g3 < 3; ++g3) {
      #pragma unroll
      for (int kk = 0; kk < 4; ++kk) {
        hg[g3] = __builtin_amdgcn_mfma_f32_16x16x32_bf16(ha[kk], whh[g3][kk], hg[g3], 0, 0, 0);
        xg[g3] = __builtin_amdgcn_mfma_f32_16x16x32_bf16(za[kk], wih[g3][kk], xg[g3], 0, 0, 0);
      }
    }

    unsigned short* hw = hbuf[(t + 1) & 1];
    f32x4 hnew;
    #pragma unroll
    for (int i = 0; i < 4; ++i) {
      float r  = fsigmoid(xg[0][i] + hg[0][i] + bias_r);
      float zt = fsigmoid(xg[1][i] + hg[1][i] + bias_z);
      float nn = ftanh(xg[2][i] + bias_in + r * (hg[2][i] + bias_hn));
      hnew[i] = nn + zt * (hreg[i] - nn);
    }
    hreg = hnew;
    if (kgrp < 2) {
      #pragma unroll
      for (int i = 0; i < 4; ++i) {
        const int r = kgrp * 4 + i;
        const int idx = r * H_ + (((jcol >> 3) ^ r) * 8) + (jcol & 7);
        hw[idx] = (unsigned short)f2bf(hnew[i]);
      }
    }
    __syncthreads();
  };

  float4 zA[4][2], zB[4][2];
  loadZ(zA, 0);
  for (int t = 0; t < T_; t += 2) {
    step(t,     zA, zB);
    step(t + 1, zB, zA);
  }

  if (kgrp < 2) {
    #pragma unroll
    for (int i = 0; i < 4; ++i) hfin[kgrp * 4 + i][jcol] = hreg[i];
  }
  __syncthreads();

  if (tid < NS * P_) {
    const int s = tid / P_, p = tid % P_;
    float acc = fc_b[p];
    const float* fw = fc_w + p * H_;
    #pragma unroll 8
    for (int j = 0; j < H_; ++j) acc += hfin[s][j] * fw[j];
    out[((size_t)bb * P_ + p) * C_ + (c0 + s)] = acc;
  }
}

extern "C" void kernel_launch(void* const* d_in, const int* in_sizes, int n_in,
                              void* d_out, int out_size, void* d_ws, size_t ws_size,
                              hipStream_t stream) {
  const float* Z    = (const float*)d_in[0];
  const float* w_ih = (const float*)d_in[1];
  const float* w_hh = (const float*)d_in[2];
  const float* b_ih = (const float*)d_in[3];
  const float* b_hh = (const float*)d_in[4];
  const float* fc_w = (const float*)d_in[5];
  const float* fc_b = (const float*)d_in[6];
  float* out = (float*)d_out;

  const size_t zt_bytes = (size_t)T_ * N_ * H_ * 2;   // 128 MiB
  if (ws_size >= zt_bytes) {
    unsigned short* Zt = (unsigned short*)d_ws;
    zconv<<<dim3(B_ * T_), 256, 0, stream>>>(Z, Zt);
    gru3<<<dim3(N_ / NS), NTHR, 0, stream>>>(Zt, w_ih, w_hh, b_ih, b_hh, fc_w, fc_b, out);
  } else {
    gru_fused<<<dim3(N_ / NS), NTHR, 0, stream>>>(Z, w_ih, w_hh, b_ih, b_hh, fc_w, fc_b, out);
  }
}

// Round 4
// 231.699 us; speedup vs baseline: 2.3846x; 1.2034x over previous
//
#include <hip/hip_runtime.h>
#include <hip/hip_bf16.h>

#define B_   32
#define T_   256
#define C_   64
#define H_   128
#define P_   10
#define N_   (B_ * C_)
#define NS   8
#define NTHR 512
#define T2   (T_ / 2)

using short8 = __attribute__((ext_vector_type(8))) short;
using f32x4  = __attribute__((ext_vector_type(4))) float;

__device__ __forceinline__ short f2bf(float f) {
  union { float f; unsigned u; } v; v.f = f;
  unsigned r = v.u + 0x7fffu + ((v.u >> 16) & 1u);   // RNE to bf16
  return (short)(r >> 16);
}
__device__ __forceinline__ float frcp(float x) { return __builtin_amdgcn_rcpf(x); }

// ---------------- Pass 1: Z (B,T,C,H) fp32 -> Zt (T, B*C, H) bf16 ----------------
__global__ __launch_bounds__(256) void zconv(const float* __restrict__ Z,
                                             unsigned short* __restrict__ Zt) {
  const int blk = blockIdx.x;
  const int b = blk >> 8;
  const int t = blk & (T_ - 1);
  const float* src = Z + ((size_t)(b * T_ + t)) * (C_ * H_);
  unsigned short* dst = Zt + ((size_t)(t * B_ + b)) * (C_ * H_);
  #pragma unroll
  for (int i = 0; i < 8; ++i) {
    const int idx = threadIdx.x + i * 256;
    float4 v = reinterpret_cast<const float4*>(src)[idx];
    short4 o;
    o.x = f2bf(v.x); o.y = f2bf(v.y); o.z = f2bf(v.z); o.w = f2bf(v.w);
    reinterpret_cast<short4*>(dst)[idx] = o;
  }
}

// ---------------- Pass 2: persistent GRU, element-split gates ----------------
__global__ __launch_bounds__(NTHR, 2) void gru4(
    const unsigned short* __restrict__ Zt,
    const float* __restrict__ w_ih,
    const float* __restrict__ w_hh,
    const float* __restrict__ b_ih,
    const float* __restrict__ b_hh,
    const float* __restrict__ fc_w,
    const float* __restrict__ fc_b,
    float* __restrict__ out)
{
  __shared__ __align__(16) unsigned short hbuf[2][NS * H_];
  __shared__ float hfin[NS][H_];

  const int tid   = threadIdx.x;
  const int wave  = tid >> 6;
  const int lane  = tid & 63;
  const int row16 = lane & 15;
  const int kgrp  = lane >> 4;
  const int srow  = row16 & 7;
  const int thalf = row16 >> 3;
  const bool low  = (kgrp < 2);
  const int rbase = (kgrp & 1) * 4;

  const int n0 = blockIdx.x * NS;
  const int bb = n0 >> 6;
  const int c0 = n0 & 63;
  const int jcol = wave * 16 + row16;

  // ---- weight B-fragments in VGPRs ----
  short8 wih[3][4], whh[3][4];
  #pragma unroll
  for (int g3 = 0; g3 < 3; ++g3) {
    const int grow = g3 * H_ + jcol;
    #pragma unroll
    for (int kk = 0; kk < 4; ++kk) {
      const float* p1 = w_ih + grow * H_ + kk * 32 + kgrp * 8;
      const float* p2 = w_hh + grow * H_ + kk * 32 + kgrp * 8;
      short8 a, c;
      #pragma unroll
      for (int e = 0; e < 8; ++e) { a[e] = f2bf(p1[e]); c[e] = f2bf(p2[e]); }
      wih[g3][kk] = a; whh[g3][kk] = c;
    }
  }

  const float bias_r  = b_ih[jcol]          + b_hh[jcol];
  const float bias_z  = b_ih[H_ + jcol]     + b_hh[H_ + jcol];
  const float bias_in = b_ih[2 * H_ + jcol];
  const float bias_hn = b_hh[2 * H_ + jcol];

  for (int i = tid; i < NS * H_; i += NTHR) hbuf[0][i] = 0;
  __syncthreads();

  // ---- hoisted LDS read ptrs (A-frag, swizzled) ----
  const unsigned short* haP[2][4];
  #pragma unroll
  for (int par = 0; par < 2; ++par)
    #pragma unroll
    for (int kk = 0; kk < 4; ++kk) {
      const int chunk = (kk * 4 + kgrp) ^ srow;
      haP[par][kk] = &hbuf[par][srow * H_ + chunk * 8];
    }

  // ---- hoisted LDS store ptrs: even step writes hbuf[1], odd writes hbuf[0] ----
  auto swz = [&](int r) { return r * H_ + (((jcol >> 3) ^ r) * 8) + (jcol & 7); };
  unsigned short* spE[2];
  unsigned short* spO[2];
  {
    const int eo = low ? 0 : 2;      // even-step row offset for this lane half
    const int oo = low ? 2 : 0;      // odd-step row offset
    #pragma unroll
    for (int j = 0; j < 2; ++j) {
      spE[j] = &hbuf[1][swz(rbase + eo + j)];
      spO[j] = &hbuf[0][swz(rbase + oo + j)];
    }
  }

  // per-lane Z base: A-rows 0-7 -> step 2p, rows 8-15 -> step 2p+1
  const unsigned short* zb = Zt + (size_t)thalf * (N_ * H_)
                               + (size_t)(n0 + srow) * H_ + kgrp * 8;
  auto loadPair = [&](short8 (&dst)[4], int p) {
    if (p > T2 - 1) p = T2 - 1;
    const unsigned short* q = zb + (size_t)(2 * p) * (N_ * H_);
    #pragma unroll
    for (int kk = 0; kk < 4; ++kk)
      dst[kk] = *reinterpret_cast<const short8*>(q + kk * 32);
  };

  auto xgFill01 = [&](f32x4 (&xg)[3], short8 (&z)[4]) {
    xg[0] = (f32x4){0.f, 0.f, 0.f, 0.f};
    xg[1] = (f32x4){0.f, 0.f, 0.f, 0.f};
    #pragma unroll
    for (int g3 = 0; g3 < 2; ++g3)
      #pragma unroll
      for (int kk = 0; kk < 4; ++kk)
        xg[g3] = __builtin_amdgcn_mfma_f32_16x16x32_bf16(z[kk], wih[g3][kk], xg[g3], 0, 0, 0);
  };
  auto xgFill2 = [&](f32x4 (&xg)[3], short8 (&z)[4]) {
    xg[2] = (f32x4){bias_in, bias_in, bias_in, bias_in};
    #pragma unroll
    for (int kk = 0; kk < 4; ++kk)
      xg[2] = __builtin_amdgcn_mfma_f32_16x16x32_bf16(z[kk], wih[2][kk], xg[2], 0, 0, 0);
  };

  // xg select arrays for current pair: xiE = this-even-step inputs, xiO = odd
  float xiE[3][2], xiO[3][2];
  auto pairTop = [&](f32x4 (&X)[3]) {
    #pragma unroll
    for (int g = 0; g < 3; ++g) {
      const float s2 = __shfl_xor(X[g][2], 32, 64);
      const float s3 = __shfl_xor(X[g][3], 32, 64);
      xiE[g][0] = low ? X[g][0] : s2;
      xiE[g][1] = low ? X[g][1] : s3;
      xiO[g][0] = low ? s2 : X[g][0];
      xiO[g][1] = low ? s3 : X[g][1];
    }
  };

  #define BAR() do { asm volatile("s_waitcnt lgkmcnt(0)" ::: "memory"); \
                     __builtin_amdgcn_s_barrier(); \
                     __builtin_amdgcn_sched_barrier(0); } while (0)

  // One GRU half-step. RBUF: hbuf index read; SPTR: store ptrs; XI: xg inputs;
  // LO/HI: hg element offsets for low/high lane halves (literal 0/2).
  #define HALFSTEP(RBUF, SPTR, XI, LO, HI)                                          \
  {                                                                                 \
    short8 ha_[4];                                                                  \
    _Pragma("unroll")                                                               \
    for (int kk = 0; kk < 4; ++kk)                                                  \
      ha_[kk] = *reinterpret_cast<const short8*>(haP[RBUF][kk]);                    \
    f32x4 hg0 = {bias_r,  bias_r,  bias_r,  bias_r};                                \
    f32x4 hg1 = {bias_z,  bias_z,  bias_z,  bias_z};                                \
    f32x4 hg2 = {bias_hn, bias_hn, bias_hn, bias_hn};                               \
    _Pragma("unroll")                                                               \
    for (int kk = 0; kk < 4; ++kk) {                                                \
      hg0 = __builtin_amdgcn_mfma_f32_16x16x32_bf16(ha_[kk], whh[0][kk], hg0, 0, 0, 0); \
      hg1 = __builtin_amdgcn_mfma_f32_16x16x32_bf16(ha_[kk], whh[1][kk], hg1, 0, 0, 0); \
      hg2 = __builtin_amdgcn_mfma_f32_16x16x32_bf16(ha_[kk], whh[2][kk], hg2, 0, 0, 0); \
    }                                                                               \
    const float i00 = low ? hg0[LO + 0] : hg0[HI + 0];                              \
    const float i01 = low ? hg0[LO + 1] : hg0[HI + 1];                              \
    const float i10 = low ? hg1[LO + 0] : hg1[HI + 0];                              \
    const float i11 = low ? hg1[LO + 1] : hg1[HI + 1];                              \
    const float i20 = low ? hg2[LO + 0] : hg2[HI + 0];                              \
    const float i21 = low ? hg2[LO + 1] : hg2[HI + 1];                              \
    const float r0 = frcp(1.0f + __expf(-(XI[0][0] + i00)));                        \
    const float r1 = frcp(1.0f + __expf(-(XI[0][1] + i01)));                        \
    const float z0 = frcp(1.0f + __expf(-(XI[1][0] + i10)));                        \
    const float z1 = frcp(1.0f + __expf(-(XI[1][1] + i11)));                        \
    const float a0 = XI[2][0] + r0 * i20;                                           \
    const float a1 = XI[2][1] + r1 * i21;                                           \
    const float nn0 = 2.0f * frcp(1.0f + __expf(-2.0f * a0)) - 1.0f;                \
    const float nn1 = 2.0f * frcp(1.0f + __expf(-2.0f * a1)) - 1.0f;                \
    hl0 = nn0 + z0 * (hcar0 - nn0);                                                 \
    hl1 = nn1 + z1 * (hcar1 - nn1);                                                 \
    unsigned pk_;                                                                   \
    asm("v_cvt_pk_bf16_f32 %0, %1, %2" : "=v"(pk_) : "v"(hl0), "v"(hl1));           \
    *(SPTR)[0] = (unsigned short)(pk_ & 0xffffu);                                   \
    *(SPTR)[1] = (unsigned short)(pk_ >> 16);                                       \
    hcar0 = __shfl_xor(hl0, 32, 64);                                                \
    hcar1 = __shfl_xor(hl1, 32, 64);                                                \
    BAR();                                                                          \
  }

  float hcar0 = 0.f, hcar1 = 0.f;   // h(t) for this lane's owned (seq,col) elems
  float hl0 = 0.f, hl1 = 0.f;       // last computed h values

  short8 zf0[4], zf1[4];
  f32x4 xgA[3], xgB[3];
  loadPair(zf0, 0);
  loadPair(zf1, 1);
  // prologue: xgA <- pair 0 (full fill)
  xgA[0] = (f32x4){0.f, 0.f, 0.f, 0.f};
  xgA[1] = (f32x4){0.f, 0.f, 0.f, 0.f};
  xgA[2] = (f32x4){bias_in, bias_in, bias_in, bias_in};
  #pragma unroll
  for (int g3 = 0; g3 < 3; ++g3)
    #pragma unroll
    for (int kk = 0; kk < 4; ++kk)
      xgA[g3] = __builtin_amdgcn_mfma_f32_16x16x32_bf16(zf0[kk], wih[g3][kk], xgA[g3], 0, 0, 0);

  for (int p = 0; p < T2; p += 2) {
    // ---- pair p: uses xgA; fills xgB from zf1; reloads zf0 ----
    pairTop(xgA);
    loadPair(zf0, p + 2);
    xgFill01(xgB, zf1);
    HALFSTEP(0, spE, xiE, 0, 2)      // even step: read hbuf[0], write hbuf[1]
    xgFill2(xgB, zf1);
    HALFSTEP(1, spO, xiO, 2, 0)      // odd step: read hbuf[1], write hbuf[0]
    // ---- pair p+1: uses xgB; fills xgA from zf0; reloads zf1 ----
    pairTop(xgB);
    loadPair(zf1, p + 3);
    xgFill01(xgA, zf0);
    HALFSTEP(0, spE, xiE, 0, 2)
    xgFill2(xgA, zf0);
    HALFSTEP(1, spO, xiO, 2, 0)
  }
  #undef HALFSTEP
  #undef BAR

  // ---- FC head: low lanes hold all 4 rows of their rbase group ----
  if (low) {
    #pragma unroll
    for (int j = 0; j < 2; ++j) {
      hfin[rbase + j][jcol]     = hcar0 * (j == 0) + hcar1 * (j == 1);
      hfin[rbase + 2 + j][jcol] = hl0   * (j == 0) + hl1   * (j == 1);
    }
    // (explicit, branch-free form of: hfin[rbase+0]=hcar0; [rbase+1]=hcar1;
    //  [rbase+2]=hl0; [rbase+3]=hl1)
    hfin[rbase + 0][jcol] = hcar0;
    hfin[rbase + 1][jcol] = hcar1;
    hfin[rbase + 2][jcol] = hl0;
    hfin[rbase + 3][jcol] = hl1;
  }
  __syncthreads();

  if (tid < NS * P_) {
    const int s = tid / P_, p = tid % P_;
    float acc = fc_b[p];
    const float* fw = fc_w + p * H_;
    #pragma unroll 8
    for (int j = 0; j < H_; ++j) acc += hfin[s][j] * fw[j];
    out[((size_t)bb * P_ + p) * C_ + (c0 + s)] = acc;
  }
}

// ---------------- Fallback (round-1 fused kernel, only if ws too small) ----------------
__device__ __forceinline__ float fsigmoid(float x) {
  x = fminf(fmaxf(x, -30.f), 30.f);
  return 1.0f / (1.0f + __expf(-x));
}
__device__ __forceinline__ float ftanh(float x) {
  x = fminf(fmaxf(x, -15.f), 15.f);
  float e = __expf(-2.0f * x);
  return (1.0f - e) / (1.0f + e);
}

__global__ __launch_bounds__(NTHR, 2) void gru_fused(
    const float* __restrict__ Z,
    const float* __restrict__ w_ih,
    const float* __restrict__ w_hh,
    const float* __restrict__ b_ih,
    const float* __restrict__ b_hh,
    const float* __restrict__ fc_w,
    const float* __restrict__ fc_b,
    float* __restrict__ out)
{
  __shared__ __align__(16) unsigned short hbuf[2][NS * H_];
  __shared__ float hfin[NS][H_];

  const int tid   = threadIdx.x;
  const int wave  = tid >> 6;
  const int lane  = tid & 63;
  const int row16 = lane & 15;
  const int kgrp  = lane >> 4;
  const int srow  = row16 & 7;

  const int n0 = blockIdx.x * NS;
  const int bb = n0 >> 6;
  const int c0 = n0 & 63;
  const int jcol = wave * 16 + row16;

  short8 wih[3][4], whh[3][4];
  #pragma unroll
  for (int g3 = 0; g3 < 3; ++g3) {
    const int grow = g3 * H_ + jcol;
    #pragma unroll
    for (int kk = 0; kk < 4; ++kk) {
      const float* p1 = w_ih + grow * H_ + kk * 32 + kgrp * 8;
      const float* p2 = w_hh + grow * H_ + kk * 32 + kgrp * 8;
      short8 a, c;
      #pragma unroll
      for (int e = 0; e < 8; ++e) { a[e] = f2bf(p1[e]); c[e] = f2bf(p2[e]); }
      wih[g3][kk] = a; whh[g3][kk] = c;
    }
  }

  const float bias_r  = b_ih[jcol]          + b_hh[jcol];
  const float bias_z  = b_ih[H_ + jcol]     + b_hh[H_ + jcol];
  const float bias_in = b_ih[2 * H_ + jcol];
  const float bias_hn = b_hh[2 * H_ + jcol];

  f32x4 hreg = {0.f, 0.f, 0.f, 0.f};
  for (int i = tid; i < NS * H_; i += NTHR) hbuf[0][i] = 0;
  __syncthreads();

  const float* zrow = Z + ((size_t)bb * T_ * C_ + (c0 + srow)) * (size_t)H_ + kgrp * 8;

  auto loadZ = [&](float4 (&zf)[4][2], int t) {
    const float* p = zrow + (size_t)t * (C_ * H_);
    #pragma unroll
    for (int kk = 0; kk < 4; ++kk) {
      zf[kk][0] = *reinterpret_cast<const float4*>(p + kk * 32);
      zf[kk][1] = *reinterpret_cast<const float4*>(p + kk * 32 + 4);
    }
  };

  auto step = [&](int t, float4 (&zcur)[4][2], float4 (&znext)[4][2]) {
    short8 za[4];
    #pragma unroll
    for (int kk = 0; kk < 4; ++kk) {
      short8 s;
      s[0] = f2bf(zcur[kk][0].x); s[1] = f2bf(zcur[kk][0].y);
      s[2] = f2bf(zcur[kk][0].z); s[3] = f2bf(zcur[kk][0].w);
      s[4] = f2bf(zcur[kk][1].x); s[5] = f2bf(zcur[kk][1].y);
      s[6] = f2bf(zcur[kk][1].z); s[7] = f2bf(zcur[kk][1].w);
      za[kk] = s;
    }
    int tn = t + 1; if (tn >= T_) tn = T_ - 1;
    loadZ(znext, tn);

    const unsigned short* hb = hbuf[t & 1];
    short8 ha[4];
    #pragma unroll
    for (int kk = 0; kk < 4; ++kk) {
      const int chunk = (kk * 4 + kgrp) ^ srow;
      ha[kk] = *reinterpret_cast<const short8*>(hb + srow * H_ + chunk * 8);
    }

    f32x4 xg[3], hg[3];
    #pragma unroll
    for (int g3 = 0; g3 < 3; ++g3) {
      xg[g3] = (f32x4){0.f, 0.f, 0.f, 0.f};
      hg[g3] = (f32x4){0.f, 0.f, 0.f, 0.f};
    }
    #pragma unroll
    for (int g3 = 0; g3 < 3; ++g3) {
      #pragma unroll
      for (int kk = 0; kk < 4; ++kk) {
        hg[g3] = __builtin_amdgcn_mfma_f32_16x16x32_bf16(ha[kk], whh[g3][kk], hg[g3], 0, 0, 0);
        xg[g3] = __builtin_amdgcn_mfma_f32_16x16x32_bf16(za[kk], wih[g3][kk], xg[g3], 0, 0, 0);
      }
    }

    unsigned short* hw = hbuf[(t + 1) & 1];
    f32x4 hnew;
    #pragma unroll
    for (int i = 0; i < 4; ++i) {
      float r  = fsigmoid(xg[0][i] + hg[0][i] + bias_r);
      float zt = fsigmoid(xg[1][i] + hg[1][i] + bias_z);
      float nn = ftanh(xg[2][i] + bias_in + r * (hg[2][i] + bias_hn));
      hnew[i] = nn + zt * (hreg[i] - nn);
    }
    hreg = hnew;
    if (kgrp < 2) {
      #pragma unroll
      for (int i = 0; i < 4; ++i) {
        const int r = kgrp * 4 + i;
        const int idx = r * H_ + (((jcol >> 3) ^ r) * 8) + (jcol & 7);
        hw[idx] = (unsigned short)f2bf(hnew[i]);
      }
    }
    __syncthreads();
  };

  float4 zA[4][2], zB[4][2];
  loadZ(zA, 0);
  for (int t = 0; t < T_; t += 2) {
    step(t,     zA, zB);
    step(t + 1, zB, zA);
  }

  if (kgrp < 2) {
    #pragma unroll
    for (int i = 0; i < 4; ++i) hfin[kgrp * 4 + i][jcol] = hreg[i];
  }
  __syncthreads();

  if (tid < NS * P_) {
    const int s = tid / P_, p = tid % P_;
    float acc = fc_b[p];
    const float* fw = fc_w + p * H_;
    #pragma unroll 8
    for (int j = 0; j < H_; ++j) acc += hfin[s][j] * fw[j];
    out[((size_t)bb * P_ + p) * C_ + (c0 + s)] = acc;
  }
}

extern "C" void kernel_launch(void* const* d_in, const int* in_sizes, int n_in,
                              void* d_out, int out_size, void* d_ws, size_t ws_size,
                              hipStream_t stream) {
  const float* Z    = (const float*)d_in[0];
  const float* w_ih = (const float*)d_in[1];
  const float* w_hh = (const float*)d_in[2];
  const float* b_ih = (const float*)d_in[3];
  const float* b_hh = (const float*)d_in[4];
  const float* fc_w = (const float*)d_in[5];
  const float* fc_b = (const float*)d_in[6];
  float* out = (float*)d_out;

  const size_t zt_bytes = (size_t)T_ * N_ * H_ * 2;   // 128 MiB
  if (ws_size >= zt_bytes) {
    unsigned short* Zt = (unsigned short*)d_ws;
    zconv<<<dim3(B_ * T_), 256, 0, stream>>>(Z, Zt);
    gru4<<<dim3(N_ / NS), NTHR, 0, stream>>>(Zt, w_ih, w_hh, b_ih, b_hh, fc_w, fc_b, out);
  } else {
    gru_fused<<<dim3(N_ / NS), NTHR, 0, stream>>>(Z, w_ih, w_hh, b_ih, b_hh, fc_w, fc_b, out);
  }
}